// Round 1
// baseline (627.285 us; speedup 1.0000x reference)
//
#include <hip/hip_runtime.h>
#include <stdint.h>

// Pipeline: scores+keys -> per-level exact top-1000 -> decode -> global order
// -> NMS suppression bitmask -> sequential greedy scan.
// Workspace layout (bytes), total ~1.93 MB:
//   keys   [86016] u64 @ 0
//   topk   [3000]  u64 @ 688128
//   order  [3000]  u32 @ 712128
//   valid  [3000]  i32 @ 724128
//   label  [3000]  i32 @ 736128
//   nbox   [3000x4]f32 @ 748128 (16B aligned)
//   sup    [3008x47]u64 @ 796128

#define N_ALL 3000
#define N_PAD 3008
#define N_WORDS 47

__device__ __forceinline__ uint32_t f32_ord(float x) {
    uint32_t u = __float_as_uint(x);
    return (u & 0x80000000u) ? ~u : (u | 0x80000000u);
}
__device__ __forceinline__ float ord_f32(uint32_t o) {
    uint32_t u = (o & 0x80000000u) ? (o & 0x7FFFFFFFu) : ~o;
    return __uint_as_float(u);
}
__device__ __forceinline__ unsigned long long shfl_u64(unsigned long long v, int src) {
    int lo = __shfl((int)(uint32_t)(v & 0xFFFFFFFFull), src);
    int hi = __shfl((int)(uint32_t)(v >> 32), src);
    return ((unsigned long long)(uint32_t)hi << 32) | (uint32_t)(unsigned)lo;
}

// ---------------- K1: per-anchor max-logit + argmax label -> unique sort key
__global__ __launch_bounds__(256) void k_scores(
        const float* __restrict__ cls0, const float* __restrict__ cls1,
        const float* __restrict__ cls2, unsigned long long* __restrict__ keys) {
    int g = blockIdx.x * blockDim.x + threadIdx.x;
    if (g >= 86016) return;
    const float* row; int local;
    if (g < 65536)      { local = g;         row = cls0 + (size_t)local * 80; }
    else if (g < 81920) { local = g - 65536; row = cls1 + (size_t)local * 80; }
    else                { local = g - 81920; row = cls2 + (size_t)local * 80; }
    const float4* r4 = (const float4*)row;
    float m = -3.4e38f; int lab = 0;
#pragma unroll
    for (int q = 0; q < 20; q++) {
        float4 v = r4[q];
        if (v.x > m) { m = v.x; lab = 4*q;   }   // strict > keeps FIRST max (jax argmax)
        if (v.y > m) { m = v.y; lab = 4*q+1; }
        if (v.z > m) { m = v.z; lab = 4*q+2; }
        if (v.w > m) { m = v.w; lab = 4*q+3; }
    }
    // key: logit desc primary, anchor index asc on ties (inverted idx), label packed low
    keys[g] = ((unsigned long long)f32_ord(m) << 32)
            | ((unsigned long long)(0x1FFFFu - (uint32_t)local) << 7)
            | (unsigned long long)lab;
}

// ---------------- K2: exact top-1000 per level (radix select + bitonic sort)
__global__ __launch_bounds__(1024) void k_select(
        const unsigned long long* __restrict__ keys,
        unsigned long long* __restrict__ topk) {
    int lvl = blockIdx.x;
    int M, off;
    if (lvl == 0)      { M = 65536; off = 0; }
    else if (lvl == 1) { M = 16384; off = 65536; }
    else               { M = 4096;  off = 81920; }
    const unsigned long long* k = keys + off;
    __shared__ unsigned int hist[8][256];
    __shared__ unsigned int merged[256];
    __shared__ unsigned long long s_prefix;
    __shared__ unsigned int s_kk, s_cnt;
    __shared__ unsigned long long skeys[1024];
    int tid = threadIdx.x;
    int cp = (tid >> 6) & 7;
    if (tid == 0) { s_prefix = 0; s_kk = 1000u; }
    __syncthreads();
    for (int d = 7; d >= 0; d--) {
        for (int i = tid; i < 2048; i += 1024) ((unsigned int*)hist)[i] = 0;
        __syncthreads();
        unsigned long long pref = s_prefix;
        for (int i = tid; i < M; i += 1024) {
            unsigned long long key = k[i];
            bool match = (d == 7) || ((key >> ((d + 1) * 8)) == pref);
            if (match) atomicAdd(&hist[cp][(uint32_t)(key >> (d * 8)) & 255u], 1u);
        }
        __syncthreads();
        if (tid < 256) {
            unsigned int s = 0;
#pragma unroll
            for (int c = 0; c < 8; c++) s += hist[c][tid];
            merged[tid] = s;
        }
        __syncthreads();
        if (tid == 0) {
            unsigned int kk = s_kk, cum = 0;
            for (int b = 255; b >= 0; b--) {
                unsigned int h = merged[b];
                if (cum + h >= kk) { s_prefix = (pref << 8) | (unsigned)b; s_kk = kk - cum; break; }
                cum += h;
            }
        }
        __syncthreads();
    }
    unsigned long long T = s_prefix;   // exact 1000th-largest key (keys unique)
    if (tid == 0) s_cnt = 0;
    __syncthreads();
    for (int i = tid; i < M; i += 1024) {
        unsigned long long key = k[i];
        if (key >= T) {
            unsigned int p = atomicAdd(&s_cnt, 1u);
            if (p < 1024u) skeys[p] = key;
        }
    }
    __syncthreads();
    unsigned int cnt = s_cnt;  // == 1000
    if (tid >= (int)cnt) skeys[tid] = 0ull;   // pad sorts last
    __syncthreads();
    // bitonic sort 1024, descending
    for (int kk2 = 2; kk2 <= 1024; kk2 <<= 1) {
        for (int j = kk2 >> 1; j > 0; j >>= 1) {
            int i = tid, ixj = i ^ j;
            if (ixj > i) {
                unsigned long long a = skeys[i], b = skeys[ixj];
                bool up = ((i & kk2) == 0);
                if (up ? (a < b) : (a > b)) { skeys[i] = b; skeys[ixj] = a; }
            }
            __syncthreads();
        }
    }
    if (tid < 1000) topk[lvl * 1000 + tid] = skeys[tid];
}

// ---------------- K3: decode boxes, write bbox/score/label outputs + NMS inputs
__global__ __launch_bounds__(256) void k_decode(
        const unsigned long long* __restrict__ topk,
        const float* __restrict__ reg0, const float* __restrict__ reg1,
        const float* __restrict__ reg2, const float* __restrict__ scales,
        float* __restrict__ out, float* __restrict__ nbox,
        int* __restrict__ nlabel, int* __restrict__ nvalid) {
    int r = blockIdx.x * blockDim.x + threadIdx.x;
    if (r >= N_ALL) return;
    int lvl = r / 1000;
    unsigned long long key = topk[r];
    uint32_t low = (uint32_t)key;
    int lab = (int)(low & 0x7Fu);
    int local = 0x1FFFF - (int)((low >> 7) & 0x1FFFFu);
    float logit = ord_f32((uint32_t)(key >> 32));
    float score = 1.0f / (1.0f + expf(-logit));
    const float* regp = (lvl == 0 ? reg0 : (lvl == 1 ? reg1 : reg2));
    float4 rg = *(const float4*)(regp + (size_t)local * 4);
    float scale = scales[lvl];
    int wlog = 8 - lvl;                       // grid width 256/128/64
    int x = local & ((1 << wlog) - 1);
    int y = local >> wlog;
    float stridef = (float)(8 << lvl);
    float ax = ((float)x + 0.5f) * stridef;
    float ay = ((float)y + 0.5f) * stridef;
    float sx = 1.0f / (1.0f + expf(-rg.x));
    float sy = 1.0f / (1.0f + expf(-rg.y));
    float cx = ax + (sx * 3.0f - 1.5f);
    float cy = ay + (sy * 3.0f - 1.5f);
    float ww = expf(rg.z * scale);
    float hh = expf(rg.w * scale);
    float b0 = (cx - 0.5f * ww) * stridef;    // reference multiplies by stride AGAIN
    float b1 = (cy - 0.5f * hh) * stridef;
    float b2 = (cx + 0.5f * ww) * stridef;
    float b3 = (cy + 0.5f * hh) * stridef;
    const float inv = 1.0f / 2048.0f;         // exact pow2, == division by 2048
    out[r * 4 + 0] = fminf(fmaxf(b0 * inv, 0.0f), 1.0f);
    out[r * 4 + 1] = fminf(fmaxf(b1 * inv, 0.0f), 1.0f);
    out[r * 4 + 2] = fminf(fmaxf(b2 * inv, 0.0f), 1.0f);
    out[r * 4 + 3] = fminf(fmaxf(b3 * inv, 0.0f), 1.0f);
    out[12000 + r] = score;
    out[15000 + r] = (float)lab;
    ((float4*)nbox)[r] = make_float4(b0, b1, b2, b3);
    nlabel[r] = lab;
    nvalid[r] = (score >= 0.05f) ? 1 : 0;
}

// ---------------- K4: global NMS order (score desc, concat idx asc), bitonic 4096
__global__ __launch_bounds__(1024) void k_order(
        const unsigned long long* __restrict__ topk, uint32_t* __restrict__ order) {
    __shared__ unsigned long long s[4096];
    int tid = threadIdx.x;
#pragma unroll
    for (int e = 0; e < 4; e++) {
        int i = e * 1024 + tid;
        unsigned long long v = 0ull;
        if (i < N_ALL)
            v = (topk[i] & 0xFFFFFFFF00000000ull) | (unsigned long long)(3000 - i);
        s[i] = v;
    }
    __syncthreads();
    for (int k = 2; k <= 4096; k <<= 1) {
        for (int j = k >> 1; j > 0; j >>= 1) {
#pragma unroll
            for (int e = 0; e < 4; e++) {
                int i = e * 1024 + tid, ixj = i ^ j;
                if (ixj > i) {
                    unsigned long long a = s[i], b = s[ixj];
                    bool up = ((i & k) == 0);
                    if (up ? (a < b) : (a > b)) { s[i] = b; s[ixj] = a; }
                }
            }
            __syncthreads();
        }
    }
#pragma unroll
    for (int e = 0; e < 3; e++) {
        int i = e * 1024 + tid;
        if (i < N_ALL) order[i] = 3000u - (uint32_t)(s[i] & 0xFFFFFFFFull);
    }
}

// ---------------- K5: suppression bitmask rows. f64 IoU WITH class offset
// (boxes reach 65536 > 8192 class spacing -> cross-class overlap possible).
__global__ __launch_bounds__(256) void k_iou(
        const uint32_t* __restrict__ order, const float* __restrict__ nbox,
        const int* __restrict__ nlabel, unsigned long long* __restrict__ sup) {
    int s = blockIdx.x;
    int tid = threadIdx.x;
    bool srow_ok = (s < N_ALL);
    double ix1 = 0, iy1 = 0, ix2 = 0, iy2 = 0, iarea = 0;
    if (srow_ok) {
        uint32_t ri = order[s];
        float4 b = ((const float4*)nbox)[ri];
        double c = (double)nlabel[ri] * 8192.0;
        ix1 = (double)b.x + c; iy1 = (double)b.y + c;
        ix2 = (double)b.z + c; iy2 = (double)b.w + c;
        iarea = (ix2 - ix1) * (iy2 - iy1);
    }
    for (int j = tid; j < N_PAD; j += 256) {
        bool sb = false;
        if (srow_ok && j < N_ALL && j > s) {
            uint32_t rj = order[j];
            float4 bj = ((const float4*)nbox)[rj];
            double cj = (double)nlabel[rj] * 8192.0;
            double jx1 = (double)bj.x + cj, jy1 = (double)bj.y + cj;
            double jx2 = (double)bj.z + cj, jy2 = (double)bj.w + cj;
            double xx1 = fmax(ix1, jx1), yy1 = fmax(iy1, jy1);
            double xx2 = fmin(ix2, jx2), yy2 = fmin(iy2, jy2);
            double w = fmax(1e-10, xx2 - xx1);
            double h = fmax(1e-10, yy2 - yy1);
            double inter = w * h;
            double jarea = (jx2 - jx1) * (jy2 - jy1);
            double iou = inter / (iarea + jarea - inter + 1e-14);
            sb = (iou > 0.6);
        }
        unsigned long long bal = __ballot(sb);
        if ((j & 63) == 0) sup[(size_t)s * N_WORDS + (j >> 6)] = bal;
    }
}

// ---------------- K6: sequential greedy scan, single wave, 64-row tiles
__global__ __launch_bounds__(64) void k_scan(
        const uint32_t* __restrict__ order, const int* __restrict__ nvalid,
        const unsigned long long* __restrict__ sup, float* __restrict__ out_keep) {
    int lane = threadIdx.x;
    unsigned long long kw = 0ull;
    if (lane < N_WORDS) {
#pragma unroll 16
        for (int b = 0; b < 64; b++) {
            int j = lane * 64 + b;
            if (j < N_ALL && nvalid[order[j]]) kw |= (1ull << b);
        }
    }
    for (int t = 0; t < N_WORDS; t++) {
        int srow = t * 64 + lane;                              // <= 3007, always valid
        unsigned long long d = sup[(size_t)srow * N_WORDS + t]; // diagonal block word
        unsigned long long km = shfl_u64(kw, t);               // keep word t (uniform)
        for (int k2 = 0; k2 < 64; k2++) {
            unsigned long long m = shfl_u64(d, k2);
            if ((km >> k2) & 1ull) km &= ~m;                   // row kept -> suppress within tile
        }
        if (lane == t) kw = km;
        if (lane < N_WORDS && lane > t) {                      // apply kept rows to future words
            unsigned long long acc = 0ull;
            const unsigned long long* rowp = sup + (size_t)t * 64 * N_WORDS + lane;
#pragma unroll 8
            for (int k2 = 0; k2 < 64; k2++) {
                unsigned long long m2 = rowp[(size_t)k2 * N_WORDS];
                acc |= (((km >> k2) & 1ull) ? m2 : 0ull);
            }
            kw &= ~acc;
        }
    }
    if (lane < N_WORDS) {
#pragma unroll 16
        for (int b = 0; b < 64; b++) {
            int j = lane * 64 + b;
            if (j < N_ALL) out_keep[order[j]] = ((kw >> b) & 1ull) ? 1.0f : 0.0f;
        }
    }
}

extern "C" void kernel_launch(void* const* d_in, const int* in_sizes, int n_in,
                              void* d_out, int out_size, void* d_ws, size_t ws_size,
                              hipStream_t stream) {
    const float* cls0   = (const float*)d_in[0];
    const float* reg0   = (const float*)d_in[1];
    const float* cls1   = (const float*)d_in[2];
    const float* reg1   = (const float*)d_in[3];
    const float* cls2   = (const float*)d_in[4];
    const float* reg2   = (const float*)d_in[5];
    const float* scales = (const float*)d_in[6];
    float* out = (float*)d_out;
    char* ws = (char*)d_ws;
    unsigned long long* keys = (unsigned long long*)(ws + 0);
    unsigned long long* topk = (unsigned long long*)(ws + 688128);
    uint32_t* order          = (uint32_t*)(ws + 712128);
    int* nvalid              = (int*)(ws + 724128);
    int* nlabel              = (int*)(ws + 736128);
    float* nbox              = (float*)(ws + 748128);
    unsigned long long* sup  = (unsigned long long*)(ws + 796128);

    k_scores<<<336, 256, 0, stream>>>(cls0, cls1, cls2, keys);
    k_select<<<3, 1024, 0, stream>>>(keys, topk);
    k_decode<<<12, 256, 0, stream>>>(topk, reg0, reg1, reg2, scales, out, nbox, nlabel, nvalid);
    k_order<<<1, 1024, 0, stream>>>(topk, order);
    k_iou<<<N_PAD, 256, 0, stream>>>(order, nbox, nlabel, sup);
    k_scan<<<1, 64, 0, stream>>>(order, nvalid, sup, out + 18000);
}

// Round 2
// 292.138 us; speedup vs baseline: 2.1472x; 2.1472x over previous
//
#include <hip/hip_runtime.h>
#include <stdint.h>

// Pipeline: scores+keys -> per-level exact top-1000 -> decode -> rank-merge order
// -> NMS suppression bitmask (+ sparsity summaries) -> sparse sequential greedy scan.
//
// Workspace layout (bytes), total ~1.28 MB (keys and sup share region: disjoint lifetimes):
//   keys   [86016] u64 @ 0        (live: k_scores..k_select)
//   sup    [3008x47]u64 @ 0       (live: k_iou..k_scan)   1131008 B
//   topk   [3000]  u64 @ 1131008
//   order  [3000]  u32 @ 1155008
//   kwinit [47]    u64 @ 1167008
//   nlabel [3000]  i32 @ 1167392
//   nbox   [3000x4]f32 @ 1179392  (16B aligned)
//   diag   [3008]  u64 @ 1227392
//   rowfut [3008]  u64 @ 1251456

#define N_ALL 3000
#define N_PAD 3008
#define N_WORDS 47

typedef unsigned long long u64;
typedef uint32_t u32;

__device__ __forceinline__ u32 f32_ord(float x) {
    u32 u = __float_as_uint(x);
    return (u & 0x80000000u) ? ~u : (u | 0x80000000u);
}
__device__ __forceinline__ float ord_f32(u32 o) {
    u32 u = (o & 0x80000000u) ? (o & 0x7FFFFFFFu) : ~o;
    return __uint_as_float(u);
}
__device__ __forceinline__ u64 shfl_u64(u64 v, int src) {
    int lo = __shfl((int)(u32)(v & 0xFFFFFFFFull), src);
    int hi = __shfl((int)(u32)(v >> 32), src);
    return ((u64)(u32)hi << 32) | (u32)(unsigned)lo;
}

// ---------------- K1: per-anchor max-logit + argmax label -> unique sort key
__global__ __launch_bounds__(256) void k_scores(
        const float* __restrict__ cls0, const float* __restrict__ cls1,
        const float* __restrict__ cls2, u64* __restrict__ keys) {
    int g = blockIdx.x * blockDim.x + threadIdx.x;
    if (g >= 86016) return;
    const float* row; int local;
    if (g < 65536)      { local = g;         row = cls0 + (size_t)local * 80; }
    else if (g < 81920) { local = g - 65536; row = cls1 + (size_t)local * 80; }
    else                { local = g - 81920; row = cls2 + (size_t)local * 80; }
    const float4* r4 = (const float4*)row;
    float m = -3.4e38f; int lab = 0;
#pragma unroll
    for (int q = 0; q < 20; q++) {
        float4 v = r4[q];
        if (v.x > m) { m = v.x; lab = 4*q;   }   // strict > keeps FIRST max (jax argmax)
        if (v.y > m) { m = v.y; lab = 4*q+1; }
        if (v.z > m) { m = v.z; lab = 4*q+2; }
        if (v.w > m) { m = v.w; lab = 4*q+3; }
    }
    // key: logit desc primary, anchor index asc on ties (inverted idx), label packed low
    keys[g] = ((u64)f32_ord(m) << 32)
            | ((u64)(0x1FFFFu - (u32)local) << 7)
            | (u64)lab;
}

// ---------------- K2: exact top-1000 per level
// radix-select: 2 full passes (16-bit prefix) -> compact candidates to LDS ->
// 6 LDS passes -> collect + bitonic sort. Global-scan fallback if compaction overflows.
__global__ __launch_bounds__(1024) void k_select(
        const u64* __restrict__ keys, u64* __restrict__ topk) {
    int lvl = blockIdx.x;
    int M, off;
    if (lvl == 0)      { M = 65536; off = 0; }
    else if (lvl == 1) { M = 16384; off = 65536; }
    else               { M = 4096;  off = 81920; }
    const u64* k = keys + off;
    __shared__ u32 hist[8][256];     // 8 KB
    __shared__ u32 merged[256];      // 1 KB
    __shared__ u64 cand[4096];       // 32 KB
    __shared__ u64 sure[1024];       // 8 KB (count provably < 1000)
    __shared__ u64 skeys[1024];      // 8 KB
    __shared__ u64 s_prefix;
    __shared__ u32 s_kk, s_scnt, s_ccnt, s_cnt, s_ovf;
    int tid = threadIdx.x;
    int cp = (tid >> 6) & 7;

    // ---- pass A: top byte over all keys
    for (int i = tid; i < 2048; i += 1024) ((u32*)hist)[i] = 0;
    if (tid == 0) { s_kk = 1000u; s_scnt = 0; s_ccnt = 0; s_cnt = 0; s_ovf = 0; }
    __syncthreads();
    for (int i = tid; i < M; i += 1024)
        atomicAdd(&hist[cp][(u32)(k[i] >> 56)], 1u);
    __syncthreads();
    if (tid < 256) { u32 s = 0;
#pragma unroll
        for (int c = 0; c < 8; c++) s += hist[c][tid];
        merged[tid] = s; }
    __syncthreads();
    if (tid == 0) {
        u32 kk = s_kk, cum = 0;
        for (int b = 255; b >= 0; b--) {
            u32 h = merged[b];
            if (cum + h >= kk) { s_prefix = (u64)b; s_kk = kk - cum; break; }
            cum += h;
        }
    }
    __syncthreads();
    u64 b7 = s_prefix;

    // ---- pass B: second byte among keys with top byte == b7
    for (int i = tid; i < 2048; i += 1024) ((u32*)hist)[i] = 0;
    __syncthreads();
    for (int i = tid; i < M; i += 1024) {
        u64 key = k[i];
        if ((key >> 56) == b7) atomicAdd(&hist[cp][(u32)(key >> 48) & 255u], 1u);
    }
    __syncthreads();
    if (tid < 256) { u32 s = 0;
#pragma unroll
        for (int c = 0; c < 8; c++) s += hist[c][tid];
        merged[tid] = s; }
    __syncthreads();
    if (tid == 0) {
        u32 kk = s_kk, cum = 0;
        for (int b = 255; b >= 0; b--) {
            u32 h = merged[b];
            if (cum + h >= kk) { s_prefix = (b7 << 8) | (u64)b; s_kk = kk - cum; break; }
            cum += h;
        }
    }
    __syncthreads();
    u64 p16 = s_prefix;

    // ---- pass B2: compact. sure = prefix16 strictly greater (all in top-k),
    //               cand = prefix16 == threshold bucket.
    for (int i = tid; i < M; i += 1024) {
        u64 key = k[i];
        u64 hp = key >> 48;
        if (hp > p16)       { u32 p = atomicAdd(&s_scnt, 1u); if (p < 1024u) sure[p] = key; }
        else if (hp == p16) { u32 p = atomicAdd(&s_ccnt, 1u);
                              if (p < 4096u) cand[p] = key; else s_ovf = 1u; }
    }
    __syncthreads();
    bool useCand = (s_ovf == 0);
    int C = (int)s_ccnt; if (C > 4096) C = 4096;

    // ---- digits 5..0
    for (int d = 5; d >= 0; d--) {
        for (int i = tid; i < 2048; i += 1024) ((u32*)hist)[i] = 0;
        __syncthreads();
        u64 pref = s_prefix;
        int sh = (d + 1) * 8;
        if (useCand) {
            for (int i = tid; i < C; i += 1024) {
                u64 key = cand[i];
                if ((key >> sh) == pref) atomicAdd(&hist[cp][(u32)(key >> (d * 8)) & 255u], 1u);
            }
        } else {
            for (int i = tid; i < M; i += 1024) {
                u64 key = k[i];
                if ((key >> sh) == pref) atomicAdd(&hist[cp][(u32)(key >> (d * 8)) & 255u], 1u);
            }
        }
        __syncthreads();
        if (tid < 256) { u32 s = 0;
#pragma unroll
            for (int c = 0; c < 8; c++) s += hist[c][tid];
            merged[tid] = s; }
        __syncthreads();
        if (tid == 0) {
            u32 kk = s_kk, cum = 0;
            for (int b = 255; b >= 0; b--) {
                u32 h = merged[b];
                if (cum + h >= kk) { s_prefix = (pref << 8) | (u64)b; s_kk = kk - cum; break; }
                cum += h;
            }
        }
        __syncthreads();
    }
    u64 T = s_prefix;   // exact 1000th-largest key (keys unique within level)

    // ---- collect exactly 1000 keys >= T
    if (useCand) {
        int ns = (int)s_scnt;
        for (int i = tid; i < ns; i += 1024) {
            u32 p = atomicAdd(&s_cnt, 1u); if (p < 1024u) skeys[p] = sure[i];
        }
        for (int i = tid; i < C; i += 1024) {
            u64 key = cand[i];
            if (key >= T) { u32 p = atomicAdd(&s_cnt, 1u); if (p < 1024u) skeys[p] = key; }
        }
    } else {
        for (int i = tid; i < M; i += 1024) {
            u64 key = k[i];
            if (key >= T) { u32 p = atomicAdd(&s_cnt, 1u); if (p < 1024u) skeys[p] = key; }
        }
    }
    __syncthreads();
    u32 cnt = s_cnt;  // == 1000
    if (tid >= (int)cnt) skeys[tid] = 0ull;   // pad sorts last
    __syncthreads();
    // bitonic sort 1024, descending
    for (int kk2 = 2; kk2 <= 1024; kk2 <<= 1) {
        for (int j = kk2 >> 1; j > 0; j >>= 1) {
            int i = tid, ixj = i ^ j;
            if (ixj > i) {
                u64 a = skeys[i], b = skeys[ixj];
                bool up = ((i & kk2) == 0);
                if (up ? (a < b) : (a > b)) { skeys[i] = b; skeys[ixj] = a; }
            }
            __syncthreads();
        }
    }
    if (tid < 1000) topk[lvl * 1000 + tid] = skeys[tid];
}

// ---------------- K3: decode boxes, write bbox/score/label outputs + NMS inputs
__global__ __launch_bounds__(256) void k_decode(
        const u64* __restrict__ topk,
        const float* __restrict__ reg0, const float* __restrict__ reg1,
        const float* __restrict__ reg2, const float* __restrict__ scales,
        float* __restrict__ out, float* __restrict__ nbox,
        int* __restrict__ nlabel) {
    int r = blockIdx.x * blockDim.x + threadIdx.x;
    if (r >= N_ALL) return;
    int lvl = r / 1000;
    u64 key = topk[r];
    u32 low = (u32)key;
    int lab = (int)(low & 0x7Fu);
    int local = 0x1FFFF - (int)((low >> 7) & 0x1FFFFu);
    float logit = ord_f32((u32)(key >> 32));
    float score = 1.0f / (1.0f + expf(-logit));
    const float* regp = (lvl == 0 ? reg0 : (lvl == 1 ? reg1 : reg2));
    float4 rg = *(const float4*)(regp + (size_t)local * 4);
    float scale = scales[lvl];
    int wlog = 8 - lvl;                       // grid width 256/128/64
    int x = local & ((1 << wlog) - 1);
    int y = local >> wlog;
    float stridef = (float)(8 << lvl);
    float ax = ((float)x + 0.5f) * stridef;
    float ay = ((float)y + 0.5f) * stridef;
    float sx = 1.0f / (1.0f + expf(-rg.x));
    float sy = 1.0f / (1.0f + expf(-rg.y));
    float cx = ax + (sx * 3.0f - 1.5f);
    float cy = ay + (sy * 3.0f - 1.5f);
    float ww = expf(rg.z * scale);
    float hh = expf(rg.w * scale);
    float b0 = (cx - 0.5f * ww) * stridef;    // reference multiplies by stride AGAIN
    float b1 = (cy - 0.5f * hh) * stridef;
    float b2 = (cx + 0.5f * ww) * stridef;
    float b3 = (cy + 0.5f * hh) * stridef;
    const float inv = 1.0f / 2048.0f;         // exact pow2, == division by 2048
    out[r * 4 + 0] = fminf(fmaxf(b0 * inv, 0.0f), 1.0f);
    out[r * 4 + 1] = fminf(fmaxf(b1 * inv, 0.0f), 1.0f);
    out[r * 4 + 2] = fminf(fmaxf(b2 * inv, 0.0f), 1.0f);
    out[r * 4 + 3] = fminf(fmaxf(b3 * inv, 0.0f), 1.0f);
    out[12000 + r] = score;
    out[15000 + r] = (float)lab;
    ((float4*)nbox)[r] = make_float4(b0, b1, b2, b3);
    nlabel[r] = lab;
}

// ---------------- K4: global NMS order by rank-merge of the 3 sorted lists.
// Tie-break across levels: earlier level wins (count >= for L2 < lvl, > for L2 > lvl).
// Also emits valid-bitmask in rank order (kwinit).
__device__ __forceinline__ int cnt_desc(const u64* __restrict__ list, u64 x, bool strict) {
    int lo = 0, hi = 1000;
    while (lo < hi) {
        int mid = (lo + hi) >> 1;
        u64 v = list[mid];
        bool in = strict ? (v > x) : (v >= x);
        if (in) lo = mid + 1; else hi = mid;
    }
    return lo;
}
__global__ __launch_bounds__(1024) void k_order(
        const u64* __restrict__ topk, u32* __restrict__ order, u64* __restrict__ kwinit) {
    __shared__ u64 lkw[N_WORDS];
    int tid = threadIdx.x;
    if (tid < N_WORDS) lkw[tid] = 0;
    __syncthreads();
#pragma unroll
    for (int e = 0; e < 3; e++) {
        int i = e * 1024 + tid;
        if (i < N_ALL) {
            u64 key = topk[i];
            int lvl = (i >= 2000) ? 2 : (i >= 1000 ? 1 : 0);
            int rank = i - lvl * 1000;
#pragma unroll
            for (int L2 = 0; L2 < 3; L2++)
                if (L2 != lvl) rank += cnt_desc(topk + L2 * 1000, key, L2 > lvl);
            order[rank] = (u32)i;
            float logit = ord_f32((u32)(key >> 32));
            float score = 1.0f / (1.0f + expf(-logit));
            if (score >= 0.05f) atomicOr(&lkw[rank >> 6], 1ull << (rank & 63));
        }
    }
    __syncthreads();
    if (tid < N_WORDS) kwinit[tid] = lkw[tid];
}

// ---------------- K5: suppression bitmask rows + sparsity summaries.
// f64 IoU WITH class offset (boxes reach 65536 > 8192 class spacing).
__global__ __launch_bounds__(256) void k_iou(
        const u32* __restrict__ order, const float* __restrict__ nbox,
        const int* __restrict__ nlabel, u64* __restrict__ sup,
        u64* __restrict__ diag, u64* __restrict__ rowfut) {
    int s = blockIdx.x;
    int tid = threadIdx.x;
    __shared__ u64 s_rf;
    if (tid == 0) s_rf = 0;
    __syncthreads();
    int tword = s >> 6;
    bool srow_ok = (s < N_ALL);
    double ix1 = 0, iy1 = 0, ix2 = 0, iy2 = 0, iarea = 0;
    if (srow_ok) {
        u32 ri = order[s];
        float4 b = ((const float4*)nbox)[ri];
        double c = (double)nlabel[ri] * 8192.0;
        ix1 = (double)b.x + c; iy1 = (double)b.y + c;
        ix2 = (double)b.z + c; iy2 = (double)b.w + c;
        iarea = (ix2 - ix1) * (iy2 - iy1);
    }
    for (int j = tid; j < N_PAD; j += 256) {
        bool sb = false;
        if (srow_ok && j < N_ALL && j > s) {
            u32 rj = order[j];
            float4 bj = ((const float4*)nbox)[rj];
            double cj = (double)nlabel[rj] * 8192.0;
            double jx1 = (double)bj.x + cj, jy1 = (double)bj.y + cj;
            double jx2 = (double)bj.z + cj, jy2 = (double)bj.w + cj;
            double xx1 = fmax(ix1, jx1), yy1 = fmax(iy1, jy1);
            double xx2 = fmin(ix2, jx2), yy2 = fmin(iy2, jy2);
            double w = fmax(1e-10, xx2 - xx1);
            double h = fmax(1e-10, yy2 - yy1);
            double inter = w * h;
            double jarea = (jx2 - jx1) * (jy2 - jy1);
            double iou = inter / (iarea + jarea - inter + 1e-14);
            sb = (iou > 0.6);
        }
        u64 bal = __ballot(sb);
        if ((j & 63) == 0) {
            int w = j >> 6;
            sup[(size_t)s * N_WORDS + w] = bal;
            if (w == tword) diag[s] = bal;
            if (w > tword && bal) atomicOr(&s_rf, 1ull << w);
        }
    }
    __syncthreads();
    if (tid == 0) rowfut[s] = s_rf;
}

// ---------------- K6: sparse sequential greedy scan, single wave.
// Per tile: coalesced diag/rowfut load (prefetched), skip-zero diagonal chain,
// apply only rows with future bits, loading only their nonzero words.
__global__ __launch_bounds__(64) void k_scan(
        const u64* __restrict__ sup, const u64* __restrict__ diag,
        const u64* __restrict__ rowfut, const u64* __restrict__ kwinit,
        const u32* __restrict__ order, float* __restrict__ out_keep) {
    int lane = threadIdx.x;
    u64 kw = (lane < N_WORDS) ? kwinit[lane] : 0ull;   // lane holds keep-word `lane`
    u64 d  = diag[lane];                               // tile 0 prefetch
    u64 rf = rowfut[lane];
    for (int t = 0; t < N_WORDS; t++) {
        u64 dn = 0, rfn = 0;
        if (t < N_WORDS - 1) {                         // prefetch next tile
            dn  = diag[(t + 1) * 64 + lane];
            rfn = rowfut[(t + 1) * 64 + lane];
        }
        u64 km = shfl_u64(kw, t);                      // keep word of this tile (uniform)
        u64 nzd = __ballot(d != 0ull);                 // rows with in-tile suppression bits
        u64 todo = nzd;
        while (true) {                                 // uniform loop, usually 0-3 iters
            u64 c = todo & km;
            if (!c) break;
            int b = __ffsll((long long)c) - 1;         // lowest unprocessed kept row
            todo &= ~(1ull << b);
            u64 m = shfl_u64(d, b);                    // its in-tile mask (bits > b only)
            km &= ~m;
        }
        if (lane == t) kw = km;
        u64 appl = km & __ballot(rf != 0ull);          // kept rows with future bits
        while (appl) {                                 // usually 0 iters
            int b = __ffsll((long long)appl) - 1;
            appl &= appl - 1;
            u64 rfb = shfl_u64(rf, b);                 // which words that row touches
            u64 m2 = 0ull;
            if (lane < N_WORDS && ((rfb >> lane) & 1ull))
                m2 = sup[(size_t)(t * 64 + b) * N_WORDS + lane];  // coalesced row slice
            kw &= ~m2;                                 // rfb bits are all > t
        }
        d = dn; rf = rfn;
    }
    if (lane < N_WORDS) {
#pragma unroll 16
        for (int b = 0; b < 64; b++) {
            int j = lane * 64 + b;
            if (j < N_ALL) out_keep[order[j]] = ((kw >> b) & 1ull) ? 1.0f : 0.0f;
        }
    }
}

extern "C" void kernel_launch(void* const* d_in, const int* in_sizes, int n_in,
                              void* d_out, int out_size, void* d_ws, size_t ws_size,
                              hipStream_t stream) {
    const float* cls0   = (const float*)d_in[0];
    const float* reg0   = (const float*)d_in[1];
    const float* cls1   = (const float*)d_in[2];
    const float* reg1   = (const float*)d_in[3];
    const float* cls2   = (const float*)d_in[4];
    const float* reg2   = (const float*)d_in[5];
    const float* scales = (const float*)d_in[6];
    float* out = (float*)d_out;
    char* ws = (char*)d_ws;
    u64* keys   = (u64*)(ws + 0);        // dead after k_select
    u64* sup    = (u64*)(ws + 0);        // written by k_iou (after keys die)
    u64* topk   = (u64*)(ws + 1131008);
    u32* order  = (u32*)(ws + 1155008);
    u64* kwinit = (u64*)(ws + 1167008);
    int* nlabel = (int*)(ws + 1167392);
    float* nbox = (float*)(ws + 1179392);
    u64* diag   = (u64*)(ws + 1227392);
    u64* rowfut = (u64*)(ws + 1251456);

    k_scores<<<336, 256, 0, stream>>>(cls0, cls1, cls2, keys);
    k_select<<<3, 1024, 0, stream>>>(keys, topk);
    k_decode<<<12, 256, 0, stream>>>(topk, reg0, reg1, reg2, scales, out, nbox, nlabel);
    k_order<<<1, 1024, 0, stream>>>(topk, order, kwinit);
    k_iou<<<N_PAD, 256, 0, stream>>>(order, nbox, nlabel, sup, diag, rowfut);
    k_scan<<<1, 64, 0, stream>>>(sup, diag, rowfut, kwinit, order, out + 18000);
}